// Round 16
// baseline (54.797 us; speedup 1.0000x reference)
//
#include <hip/hip_runtime.h>

#define NB 8192
#define ND 128
#define NC 1000
#define NCH 64    // chunks of 128 rows
#define CHS 128   // chunk size
#define SL 6      // b-chunks per strip block
#define NBLK 374  // sum over a of ceil((64-a)/6)
#define CAP 64    // bucket capacity per class
#define NRB (NB / 4)  // reduce blocks

typedef __attribute__((ext_vector_type(8))) short bf16x8;
typedef __attribute__((ext_vector_type(4))) float f32x4;

__device__ __forceinline__ unsigned short f2bf(float f) {
    unsigned int u = __float_as_uint(f);
    return (unsigned short)((u + 0x7fffu + ((u >> 16) & 1u)) >> 16);
}

// ---------------- CE (label smoothing) fused with emb->bf16 conversion + cnt zeroing ---------
__global__ __launch_bounds__(256) void ce_prep_kernel(const float* __restrict__ logits,
                                                      const float* __restrict__ emb,
                                                      const int* __restrict__ labels,
                                                      unsigned short* __restrict__ ebf,
                                                      float* __restrict__ cls_part,
                                                      int* __restrict__ cnt) {
    int wave = threadIdx.x >> 6, lane = threadIdx.x & 63;
    int r = blockIdx.x * 4 + wave;

    if (blockIdx.x == 0) {
        for (int k = threadIdx.x; k < NC; k += 256) cnt[k] = 0;
    }

    {
        const float* erow = emb + (size_t)r * ND;
        float2 v = *(const float2*)(erow + lane * 2);
        unsigned int packed = (unsigned int)f2bf(v.x) | ((unsigned int)f2bf(v.y) << 16);
        *(unsigned int*)(ebf + (size_t)r * ND + lane * 2) = packed;
    }

    const float* x = logits + (size_t)r * NC;
    float4 q0 = *(const float4*)(x + 4 * lane);
    float4 q1 = *(const float4*)(x + 256 + 4 * lane);
    float4 q2 = *(const float4*)(x + 512 + 4 * lane);
    float4 q3;
    bool a3 = (192 + lane) < 250;
    if (a3) q3 = *(const float4*)(x + 768 + 4 * lane);
    else q3 = make_float4(-3.4e38f, -3.4e38f, -3.4e38f, -3.4e38f);

    float m = fmaxf(fmaxf(fmaxf(q0.x, q0.y), fmaxf(q0.z, q0.w)),
                    fmaxf(fmaxf(q1.x, q1.y), fmaxf(q1.z, q1.w)));
    m = fmaxf(m, fmaxf(fmaxf(q2.x, q2.y), fmaxf(q2.z, q2.w)));
    m = fmaxf(m, fmaxf(fmaxf(q3.x, q3.y), fmaxf(q3.z, q3.w)));
    float s = (q0.x + q0.y + q0.z + q0.w) + (q1.x + q1.y + q1.z + q1.w) +
              (q2.x + q2.y + q2.z + q2.w) +
              (a3 ? (q3.x + q3.y + q3.z + q3.w) : 0.f);
#pragma unroll
    for (int o = 32; o >= 1; o >>= 1) {
        m = fmaxf(m, __shfl_xor(m, o));
        s += __shfl_xor(s, o);
    }
    float se = expf(q0.x - m) + expf(q0.y - m) + expf(q0.z - m) + expf(q0.w - m) +
               expf(q1.x - m) + expf(q1.y - m) + expf(q1.z - m) + expf(q1.w - m) +
               expf(q2.x - m) + expf(q2.y - m) + expf(q2.z - m) + expf(q2.w - m) +
               expf(q3.x - m) + expf(q3.y - m) + expf(q3.z - m) + expf(q3.w - m);
#pragma unroll
    for (int o = 32; o >= 1; o >>= 1) se += __shfl_xor(se, o);
    float xl = x[labels[r]];
    float v = (m + logf(se)) - 0.9f * xl - 0.1f * (s * (1.0f / NC));
    if (lane == 0) cls_part[r] = v;
}

// ---------------- bucket: per-class row lists (order nondeterministic, consumers tie-break) ---
__global__ __launch_bounds__(256) void bucket_kernel(const int* __restrict__ labels,
                                                     int* __restrict__ cnt,
                                                     int* __restrict__ lists) {
    int r = blockIdx.x * 256 + threadIdx.x;
    int c = labels[r];
    int slot = atomicAdd(&cnt[c], 1);
    if (slot < CAP) lists[c * CAP + slot] = r;
}

// ---------------- mining: SYMMETRIC STRIPS — block owns chunk a, walks up to 6 b-chunks ------
// 374 blocks x 4 waves, all resident (2 blocks/CU). A-frags loaded once per block; b-tiles
// double-buffered (prefetch issued before sweep -> only the first stage is latency-exposed).
// part[r][c]: row-side part[i in a][b]; col-side part[j in b][a] (diagonal col-write skipped).
__global__ __launch_bounds__(256, 2) void mine_kernel(const unsigned short* __restrict__ ebf,
                                                      const int* __restrict__ labels,
                                                      float* __restrict__ part) {
    __shared__ unsigned short btile[2][CHS * ND];  // 2 x 32 KB
    __shared__ float colbuf[2][4][CHS];            // 4 KB (parity-buffered)
    __shared__ int lj_lds[SL * CHS];               // 3 KB strip labels
    int tid = threadIdx.x;
    int wave = tid >> 6, lane = tid & 63;
    int col = lane & 15, grp = lane >> 4;

    // strip decode: blockIdx.x -> (a, strip k) ; b0 = a + 6k
    int s = blockIdx.x, a = 0;
    while (s >= (NCH - a + SL - 1) / SL) { s -= (NCH - a + SL - 1) / SL; ++a; }
    int b0 = a + SL * s;
    int ibase = a * CHS + wave * 32;

    // stage one 128-row chunk: XOR-swizzled global source -> linear LDS dest (rule #21)
#define STAGE(buf, jb0)                                                              \
    do {                                                                             \
        _Pragma("unroll")                                                            \
        for (int rep = 0; rep < 8; ++rep) {                                          \
            int row = (tid >> 4) + rep * 16;                                         \
            const unsigned short* src =                                              \
                ebf + (size_t)((jb0) + row) * ND + (((tid & 15) ^ (row & 7)) << 3);  \
            unsigned short* dst =                                                    \
                &btile[buf][0] + (size_t)((tid >> 6) * 4 + rep * 16) * ND;           \
            __builtin_amdgcn_global_load_lds(                                        \
                (const __attribute__((address_space(1))) unsigned int*)src,          \
                (__attribute__((address_space(3))) unsigned int*)dst, 16, 0, 0);     \
        }                                                                            \
    } while (0)

    STAGE(0, b0 * CHS);

    // strip labels -> LDS (clamped; out-of-range strips never consumed)
    for (int k = tid; k < SL * CHS; k += 256) {
        int idx = b0 * CHS + k;
        lj_lds[k] = labels[min(idx, NB - 1)];
    }

    // A fragments: 2 i-chunks x 4 k-chunks, registers for whole block lifetime
    bf16x8 af[2][4];
#pragma unroll
    for (int ic = 0; ic < 2; ++ic) {
        const unsigned short* ap = ebf + (size_t)(ibase + ic * 16 + col) * ND + (grp << 3);
#pragma unroll
        for (int kc = 0; kc < 4; ++kc) af[ic][kc] = *(const bf16x8*)(ap + kc * 32);
    }
    int li[8];
#pragma unroll
    for (int ic = 0; ic < 2; ++ic)
#pragma unroll
        for (int r = 0; r < 4; ++r) li[ic * 4 + r] = labels[ibase + ic * 16 + grp * 4 + r];

    __syncthreads();  // drains stage(0) + labels + A loads

    for (int t = 0; t < SL; ++t) {
        int b = b0 + t;
        if (b >= NCH) break;
        int cur = t & 1;
        if (t + 1 < SL && b + 1 < NCH) STAGE(cur ^ 1, (b + 1) * CHS);  // prefetch next b

        int jbase = b * CHS;
        float bn[8], colmax[8];
#pragma unroll
        for (int k = 0; k < 8; ++k) { bn[k] = -3.4e38f; colmax[k] = -3.4e38f; }

        const unsigned short* bt = &btile[cur][0];
#pragma unroll
        for (int st = 0; st < 8; ++st) {
            bf16x8 bfr[4];
#pragma unroll
            for (int kc = 0; kc < 4; ++kc) {
                int chunk = (grp + 4 * kc) ^ (col & 7);
                bfr[kc] = *(const bf16x8*)(bt + (size_t)(st * 16 + col) * ND + chunk * 8);
            }
            f32x4 acc[2] = {{0.f, 0.f, 0.f, 0.f}, {0.f, 0.f, 0.f, 0.f}};
#pragma unroll
            for (int kc = 0; kc < 4; ++kc)
#pragma unroll
                for (int ic = 0; ic < 2; ++ic)
                    acc[ic] = __builtin_amdgcn_mfma_f32_16x16x32_bf16(af[ic][kc], bfr[kc],
                                                                      acc[ic], 0, 0, 0);
            int lj = lj_lds[t * CHS + st * 16 + col];
            float cm = -3.4e38f;
#pragma unroll
            for (int ic = 0; ic < 2; ++ic)
#pragma unroll
                for (int r = 0; r < 4; ++r) {
                    // same-class mask (includes self on diagonal) used for BOTH sides
                    float mv = (lj == li[ic * 4 + r]) ? -3.4e38f : acc[ic][r];
                    bn[ic * 4 + r] = fmaxf(bn[ic * 4 + r], mv);
                    cm = fmaxf(cm, mv);
                }
            cm = fmaxf(cm, __shfl_xor(cm, 16));
            cm = fmaxf(cm, __shfl_xor(cm, 32));
            colmax[st] = cm;
        }

        // row-side: reduce over 16 cols, write part[i][b]
#pragma unroll
        for (int k = 0; k < 8; ++k)
#pragma unroll
            for (int msk = 1; msk <= 8; msk <<= 1)
                bn[k] = fmaxf(bn[k], __shfl_xor(bn[k], msk));
        if (col == 0) {
#pragma unroll
            for (int ic = 0; ic < 2; ++ic)
#pragma unroll
                for (int r = 0; r < 4; ++r) {
                    int gi = ibase + ic * 16 + grp * 4 + r;
                    part[(size_t)gi * NCH + b] = bn[ic * 4 + r];
                }
        }

        // col-side partials into parity colbuf
        if (lane < 16) {
#pragma unroll
            for (int st = 0; st < 8; ++st) colbuf[cur][wave][st * 16 + lane] = colmax[st];
        }
        __syncthreads();  // publishes colbuf[cur] AND btile[cur^1] (drains prefetch)
        if (b != a && tid < CHS) {
            float m = fmaxf(fmaxf(colbuf[cur][0][tid], colbuf[cur][1][tid]),
                            fmaxf(colbuf[cur][2][tid], colbuf[cur][3][tid]));
            part[(size_t)(jbase + tid) * NCH + a] = m;
        }
    }
#undef STAGE
}

// ---------------- reduce: neg from 64 mined partials; pos via parallel candidate scan --------
__global__ __launch_bounds__(256) void reduce_kernel(const float* __restrict__ e,
                                                     const int* __restrict__ labels,
                                                     const float* __restrict__ part,
                                                     const int* __restrict__ cnt,
                                                     const int* __restrict__ lists,
                                                     const float* __restrict__ cls_part,
                                                     float4* __restrict__ blk) {
    __shared__ float sp[4], sv[4], sc[4];
    int wave = threadIdx.x >> 6, lane = threadIdx.x & 63;
    int r = blockIdx.x * 4 + wave;
    int g = lane >> 3, sl = lane & 7;

    // merge 64 neg partials (value-only max, full-wave butterfly)
    float nb = part[(size_t)r * NCH + lane];
#pragma unroll
    for (int o = 1; o <= 32; o <<= 1) nb = fmaxf(nb, __shfl_xor(nb, o));
    float d_an = sqrtf(fmaxf(2.0f - 2.0f * nb, 0.0f));

    int myl = labels[r];
    int ctot = cnt[myl];
    int n = min(ctot, CAP);
    const float* a = e + (size_t)r * ND;

    float4 a0 = *(const float4*)(a + sl * 16);
    float4 a1 = *(const float4*)(a + sl * 16 + 4);
    float4 a2 = *(const float4*)(a + sl * 16 + 8);
    float4 a3 = *(const float4*)(a + sl * 16 + 12);

    float best = -1.0f;
    int jp = r;
    for (int base = 0; base < n; base += 8) {
        int idx = base + g;
        bool ok = (idx < n);
        int j2 = ok ? lists[myl * CAP + idx] : r;
        const float* p = e + (size_t)j2 * ND;
        float4 p0 = *(const float4*)(p + sl * 16);
        float4 p1 = *(const float4*)(p + sl * 16 + 4);
        float4 p2 = *(const float4*)(p + sl * 16 + 8);
        float4 p3 = *(const float4*)(p + sl * 16 + 12);
        float d, ss = 0.f;
        d = a0.x - p0.x; ss += d * d; d = a0.y - p0.y; ss += d * d;
        d = a0.z - p0.z; ss += d * d; d = a0.w - p0.w; ss += d * d;
        d = a1.x - p1.x; ss += d * d; d = a1.y - p1.y; ss += d * d;
        d = a1.z - p1.z; ss += d * d; d = a1.w - p1.w; ss += d * d;
        d = a2.x - p2.x; ss += d * d; d = a2.y - p2.y; ss += d * d;
        d = a2.z - p2.z; ss += d * d; d = a2.w - p2.w; ss += d * d;
        d = a3.x - p3.x; ss += d * d; d = a3.y - p3.y; ss += d * d;
        d = a3.z - p3.z; ss += d * d; d = a3.w - p3.w; ss += d * d;
        ss += __shfl_xor(ss, 1);
        ss += __shfl_xor(ss, 2);
        ss += __shfl_xor(ss, 4);  // group-uniform d2
        float d2v = (ok && j2 != r) ? ss : -2.0f;
        if (d2v > best || (d2v == best && j2 < jp)) { best = d2v; jp = j2; }
    }
#pragma unroll
    for (int msk = 8; msk <= 32; msk <<= 1) {
        float ob = __shfl_xor(best, msk);
        int oj = __shfl_xor(jp, msk);
        if (ob > best || (ob == best && oj < jp)) { best = ob; jp = oj; }
    }
    bool valid = (ctot >= 2) && (ctot < NB);

    // winner recomputed with torch's +eps inside the norm (jp==r when none: unused)
    const float* p = e + (size_t)jp * ND;
    float2 av = *(const float2*)(a + lane * 2);
    float2 pv = *(const float2*)(p + lane * 2);
    float dx = av.x - pv.x + 1e-6f, dy = av.y - pv.y + 1e-6f;
    float ss = dx * dx + dy * dy;
#pragma unroll
    for (int o = 32; o >= 1; o >>= 1) ss += __shfl_xor(ss, o);
    float d_ap = sqrtf(ss);

    if (lane == 0) {
        sp[wave] = valid ? fmaxf(d_ap - d_an + 0.5f, 0.0f) : 0.0f;
        sv[wave] = valid ? 1.0f : 0.0f;
        sc[wave] = cls_part[r];
    }
    __syncthreads();
    if (threadIdx.x == 0)
        blk[blockIdx.x] = make_float4(sp[0] + sp[1] + sp[2] + sp[3],
                                      sv[0] + sv[1] + sv[2] + sv[3],
                                      sc[0] + sc[1] + sc[2] + sc[3], 0.f);
}

// ---------------- final combine: single block tree-reduces 2048 block partials ---------------
__global__ __launch_bounds__(1024) void fin_kernel(const float4* __restrict__ blk,
                                                   float* __restrict__ out) {
    __shared__ float sc[16], sp[16], sn[16];
    int t = threadIdx.x;
    int wave = t >> 6, lane = t & 63;
    float tp = 0.f, tv = 0.f, c = 0.f;
    for (int k = t; k < NRB; k += 1024) {
        float4 q = blk[k];
        tp += q.x;
        tv += q.y;
        c += q.z;
    }
#pragma unroll
    for (int o = 32; o >= 1; o >>= 1) {
        tp += __shfl_xor(tp, o);
        tv += __shfl_xor(tv, o);
        c += __shfl_xor(c, o);
    }
    if (lane == 0) { sp[wave] = tp; sn[wave] = tv; sc[wave] = c; }
    __syncthreads();
    if (t == 0) {
        float P = 0.f, V = 0.f, C = 0.f;
        for (int w = 0; w < 16; ++w) { P += sp[w]; V += sn[w]; C += sc[w]; }
        float tri = V > 0.5f ? P / V : 0.0f;
        out[0] = C * (1.0f / NB) + tri;
    }
}

extern "C" void kernel_launch(void* const* d_in, const int* in_sizes, int n_in,
                              void* d_out, int out_size, void* d_ws, size_t ws_size,
                              hipStream_t stream) {
    const float* logits = (const float*)d_in[0];
    const float* emb = (const float*)d_in[1];
    const int* labels = (const int*)d_in[2];

    char* w = (char*)d_ws;
    unsigned short* ebf = (unsigned short*)w;                 // 2 MB
    float* part = (float*)(w + 2097152);                      // NB*64 f32 (2 MB)
    float* cls_part = (float*)(w + 4194304);                  // NB f32 (32 KB)
    int* cnt = (int*)(w + 4227072);                           // NC int (4 KB)
    int* lists = (int*)(w + 4231168);                         // NC*CAP int (256 KB)
    float4* blk = (float4*)(w + 4493312);                     // NRB float4 (32 KB)

    ce_prep_kernel<<<NB / 4, 256, 0, stream>>>(logits, emb, labels, ebf, cls_part, cnt);
    bucket_kernel<<<NB / 256, 256, 0, stream>>>(labels, cnt, lists);
    mine_kernel<<<NBLK, 256, 0, stream>>>(ebf, labels, part);
    reduce_kernel<<<NRB, 256, 0, stream>>>(emb, labels, part, cnt, lists, cls_part, blk);
    fin_kernel<<<1, 1024, 0, stream>>>(blk, (float*)d_out);
}

// Round 17
// 46.905 us; speedup vs baseline: 1.1682x; 1.1682x over previous
//
#include <hip/hip_runtime.h>

#define NB 8192
#define ND 128
#define NC 1000
#define NCH 64    // chunks of 128 rows
#define CHS 128   // chunk size
#define NPAIR (NCH * (NCH + 1) / 2)  // 2080 triangular chunk-pairs
#define CAP 64    // bucket capacity per class
#define NRB (NB / 4)  // reduce blocks

typedef __attribute__((ext_vector_type(8))) short bf16x8;
typedef __attribute__((ext_vector_type(4))) float f32x4;

__device__ __forceinline__ unsigned short f2bf(float f) {
    unsigned int u = __float_as_uint(f);
    return (unsigned short)((u + 0x7fffu + ((u >> 16) & 1u)) >> 16);
}

// ---------------- CE (label smoothing) fused with emb->bf16 conversion + cnt zeroing ---------
__global__ __launch_bounds__(256) void ce_prep_kernel(const float* __restrict__ logits,
                                                      const float* __restrict__ emb,
                                                      const int* __restrict__ labels,
                                                      unsigned short* __restrict__ ebf,
                                                      float* __restrict__ cls_part,
                                                      int* __restrict__ cnt) {
    int wave = threadIdx.x >> 6, lane = threadIdx.x & 63;
    int r = blockIdx.x * 4 + wave;

    if (blockIdx.x == 0) {
        for (int k = threadIdx.x; k < NC; k += 256) cnt[k] = 0;
    }

    {
        const float* erow = emb + (size_t)r * ND;
        float2 v = *(const float2*)(erow + lane * 2);
        unsigned int packed = (unsigned int)f2bf(v.x) | ((unsigned int)f2bf(v.y) << 16);
        *(unsigned int*)(ebf + (size_t)r * ND + lane * 2) = packed;
    }

    const float* x = logits + (size_t)r * NC;
    float4 q0 = *(const float4*)(x + 4 * lane);
    float4 q1 = *(const float4*)(x + 256 + 4 * lane);
    float4 q2 = *(const float4*)(x + 512 + 4 * lane);
    float4 q3;
    bool a3 = (192 + lane) < 250;
    if (a3) q3 = *(const float4*)(x + 768 + 4 * lane);
    else q3 = make_float4(-3.4e38f, -3.4e38f, -3.4e38f, -3.4e38f);

    float m = fmaxf(fmaxf(fmaxf(q0.x, q0.y), fmaxf(q0.z, q0.w)),
                    fmaxf(fmaxf(q1.x, q1.y), fmaxf(q1.z, q1.w)));
    m = fmaxf(m, fmaxf(fmaxf(q2.x, q2.y), fmaxf(q2.z, q2.w)));
    m = fmaxf(m, fmaxf(fmaxf(q3.x, q3.y), fmaxf(q3.z, q3.w)));
    float s = (q0.x + q0.y + q0.z + q0.w) + (q1.x + q1.y + q1.z + q1.w) +
              (q2.x + q2.y + q2.z + q2.w) +
              (a3 ? (q3.x + q3.y + q3.z + q3.w) : 0.f);
#pragma unroll
    for (int o = 32; o >= 1; o >>= 1) {
        m = fmaxf(m, __shfl_xor(m, o));
        s += __shfl_xor(s, o);
    }
    float se = expf(q0.x - m) + expf(q0.y - m) + expf(q0.z - m) + expf(q0.w - m) +
               expf(q1.x - m) + expf(q1.y - m) + expf(q1.z - m) + expf(q1.w - m) +
               expf(q2.x - m) + expf(q2.y - m) + expf(q2.z - m) + expf(q2.w - m) +
               expf(q3.x - m) + expf(q3.y - m) + expf(q3.z - m) + expf(q3.w - m);
#pragma unroll
    for (int o = 32; o >= 1; o >>= 1) se += __shfl_xor(se, o);
    float xl = x[labels[r]];
    float v = (m + logf(se)) - 0.9f * xl - 0.1f * (s * (1.0f / NC));
    if (lane == 0) cls_part[r] = v;
}

// ---------------- mining: SYMMETRIC chunk-pairs (R15 structure) + folded-in bucket ----------
// 2080 blocks x 4 waves; wave owns 32 i-rows of chunk a; chunk b (128 j) staged once in LDS.
// Blocks 0..31 additionally build the class buckets (cnt zeroed by ce_prep; reduce consumes
// after this kernel completes; list order nondeterminism neutralized by reduce's tie-break).
__global__ __launch_bounds__(256, 4) void mine_kernel(const unsigned short* __restrict__ ebf,
                                                      const int* __restrict__ labels,
                                                      int* __restrict__ cnt,
                                                      int* __restrict__ lists,
                                                      float* __restrict__ part) {
    __shared__ unsigned short btile[CHS * ND];  // 32 KB, static after prologue
    __shared__ float colbuf[4][CHS];            // 2 KB
    int tid = threadIdx.x;
    int wave = tid >> 6, lane = tid & 63;
    int col = lane & 15, grp = lane >> 4;

    // folded bucket: first NB/256 blocks insert their rows
    if (blockIdx.x < NB / 256) {
        int r = blockIdx.x * 256 + tid;
        int c = labels[r];
        int slot = atomicAdd(&cnt[c], 1);
        if (slot < CAP) lists[c * CAP + slot] = r;
    }

    // triangular decode: blockIdx.x -> (a, b), a <= b
    int t = blockIdx.x, a = 0;
    while (t >= NCH - a) { t -= NCH - a; ++a; }
    int b = a + t;

    int ibase = a * CHS + wave * 32;
    int jbase = b * CHS;

    // stage chunk b: XOR-swizzled global source -> linear LDS dest (rule #21)
#pragma unroll
    for (int rep = 0; rep < 8; ++rep) {
        int row = (tid >> 4) + rep * 16;
        const unsigned short* src =
            ebf + (size_t)(jbase + row) * ND + (((tid & 15) ^ (row & 7)) << 3);
        unsigned short* dst = btile + (size_t)((tid >> 6) * 4 + rep * 16) * ND;
        __builtin_amdgcn_global_load_lds(
            (const __attribute__((address_space(1))) unsigned int*)src,
            (__attribute__((address_space(3))) unsigned int*)dst, 16, 0, 0);
    }

    // A fragments: 2 i-chunks x 4 k-chunks
    bf16x8 af[2][4];
#pragma unroll
    for (int ic = 0; ic < 2; ++ic) {
        const unsigned short* ap = ebf + (size_t)(ibase + ic * 16 + col) * ND + (grp << 3);
#pragma unroll
        for (int kc = 0; kc < 4; ++kc) af[ic][kc] = *(const bf16x8*)(ap + kc * 32);
    }
    int li[8];
#pragma unroll
    for (int ic = 0; ic < 2; ++ic)
#pragma unroll
        for (int r = 0; r < 4; ++r) li[ic * 4 + r] = labels[ibase + ic * 16 + grp * 4 + r];
    int ljall[8];
#pragma unroll
    for (int st = 0; st < 8; ++st) ljall[st] = labels[jbase + st * 16 + col];

    float bn[8];
    float colmax[8];
#pragma unroll
    for (int k = 0; k < 8; ++k) { bn[k] = -3.4e38f; colmax[k] = -3.4e38f; }

    __syncthreads();  // drains stage + A/label loads; btile static hereafter

#pragma unroll
    for (int st = 0; st < 8; ++st) {
        bf16x8 bfr[4];
#pragma unroll
        for (int kc = 0; kc < 4; ++kc) {
            int chunk = (grp + 4 * kc) ^ (col & 7);
            bfr[kc] = *(const bf16x8*)(btile + (size_t)(st * 16 + col) * ND + chunk * 8);
        }
        f32x4 acc[2] = {{0.f, 0.f, 0.f, 0.f}, {0.f, 0.f, 0.f, 0.f}};
#pragma unroll
        for (int kc = 0; kc < 4; ++kc)
#pragma unroll
            for (int ic = 0; ic < 2; ++ic)
                acc[ic] = __builtin_amdgcn_mfma_f32_16x16x32_bf16(af[ic][kc], bfr[kc],
                                                                  acc[ic], 0, 0, 0);
        int lj = ljall[st];
        float cm = -3.4e38f;
#pragma unroll
        for (int ic = 0; ic < 2; ++ic)
#pragma unroll
            for (int r = 0; r < 4; ++r) {
                // same-class mask (includes self on diagonal blocks) used for BOTH sides
                float mv = (lj == li[ic * 4 + r]) ? -3.4e38f : acc[ic][r];
                bn[ic * 4 + r] = fmaxf(bn[ic * 4 + r], mv);
                cm = fmaxf(cm, mv);
            }
        // column partial: max over this wave's 64 i-rows (cross-grp combine)
        cm = fmaxf(cm, __shfl_xor(cm, 16));
        cm = fmaxf(cm, __shfl_xor(cm, 32));
        colmax[st] = cm;
    }

    // row-side: reduce over 16 cols, write part[i][b]
#pragma unroll
    for (int k = 0; k < 8; ++k)
#pragma unroll
        for (int msk = 1; msk <= 8; msk <<= 1)
            bn[k] = fmaxf(bn[k], __shfl_xor(bn[k], msk));
    if (col == 0) {
#pragma unroll
        for (int ic = 0; ic < 2; ++ic)
#pragma unroll
            for (int r = 0; r < 4; ++r) {
                int gi = ibase + ic * 16 + grp * 4 + r;
                part[(size_t)gi * NCH + b] = bn[ic * 4 + r];
            }
    }

    // col-side: merge 4 waves' column partials, write part[j][a] (skip on diagonal)
    if (a != b) {
        if (lane < 16) {
#pragma unroll
            for (int st = 0; st < 8; ++st) colbuf[wave][st * 16 + lane] = colmax[st];
        }
        __syncthreads();
        if (tid < CHS) {
            float m = fmaxf(fmaxf(colbuf[0][tid], colbuf[1][tid]),
                            fmaxf(colbuf[2][tid], colbuf[3][tid]));
            part[(size_t)(jbase + tid) * NCH + a] = m;
        }
    }
}

// ---------------- reduce: neg from 64 mined partials; pos via parallel candidate scan --------
__global__ __launch_bounds__(256) void reduce_kernel(const float* __restrict__ e,
                                                     const int* __restrict__ labels,
                                                     const float* __restrict__ part,
                                                     const int* __restrict__ cnt,
                                                     const int* __restrict__ lists,
                                                     const float* __restrict__ cls_part,
                                                     float4* __restrict__ blk) {
    __shared__ float sp[4], sv[4], sc[4];
    int wave = threadIdx.x >> 6, lane = threadIdx.x & 63;
    int r = blockIdx.x * 4 + wave;
    int g = lane >> 3, sl = lane & 7;

    // merge 64 neg partials (value-only max, full-wave butterfly)
    float nb = part[(size_t)r * NCH + lane];
#pragma unroll
    for (int o = 1; o <= 32; o <<= 1) nb = fmaxf(nb, __shfl_xor(nb, o));
    float d_an = sqrtf(fmaxf(2.0f - 2.0f * nb, 0.0f));

    int myl = labels[r];
    int ctot = cnt[myl];
    int n = min(ctot, CAP);
    const float* a = e + (size_t)r * ND;

    float4 a0 = *(const float4*)(a + sl * 16);
    float4 a1 = *(const float4*)(a + sl * 16 + 4);
    float4 a2 = *(const float4*)(a + sl * 16 + 8);
    float4 a3 = *(const float4*)(a + sl * 16 + 12);

    float best = -1.0f;
    int jp = r;
    for (int base = 0; base < n; base += 8) {
        int idx = base + g;
        bool ok = (idx < n);
        int j2 = ok ? lists[myl * CAP + idx] : r;
        const float* p = e + (size_t)j2 * ND;
        float4 p0 = *(const float4*)(p + sl * 16);
        float4 p1 = *(const float4*)(p + sl * 16 + 4);
        float4 p2 = *(const float4*)(p + sl * 16 + 8);
        float4 p3 = *(const float4*)(p + sl * 16 + 12);
        float d, ss = 0.f;
        d = a0.x - p0.x; ss += d * d; d = a0.y - p0.y; ss += d * d;
        d = a0.z - p0.z; ss += d * d; d = a0.w - p0.w; ss += d * d;
        d = a1.x - p1.x; ss += d * d; d = a1.y - p1.y; ss += d * d;
        d = a1.z - p1.z; ss += d * d; d = a1.w - p1.w; ss += d * d;
        d = a2.x - p2.x; ss += d * d; d = a2.y - p2.y; ss += d * d;
        d = a2.z - p2.z; ss += d * d; d = a2.w - p2.w; ss += d * d;
        d = a3.x - p3.x; ss += d * d; d = a3.y - p3.y; ss += d * d;
        d = a3.z - p3.z; ss += d * d; d = a3.w - p3.w; ss += d * d;
        ss += __shfl_xor(ss, 1);
        ss += __shfl_xor(ss, 2);
        ss += __shfl_xor(ss, 4);  // group-uniform d2
        float d2v = (ok && j2 != r) ? ss : -2.0f;
        if (d2v > best || (d2v == best && j2 < jp)) { best = d2v; jp = j2; }
    }
#pragma unroll
    for (int msk = 8; msk <= 32; msk <<= 1) {
        float ob = __shfl_xor(best, msk);
        int oj = __shfl_xor(jp, msk);
        if (ob > best || (ob == best && oj < jp)) { best = ob; jp = oj; }
    }
    bool valid = (ctot >= 2) && (ctot < NB);

    // winner recomputed with torch's +eps inside the norm (jp==r when none: unused)
    const float* p = e + (size_t)jp * ND;
    float2 av = *(const float2*)(a + lane * 2);
    float2 pv = *(const float2*)(p + lane * 2);
    float dx = av.x - pv.x + 1e-6f, dy = av.y - pv.y + 1e-6f;
    float ss = dx * dx + dy * dy;
#pragma unroll
    for (int o = 32; o >= 1; o >>= 1) ss += __shfl_xor(ss, o);
    float d_ap = sqrtf(ss);

    if (lane == 0) {
        sp[wave] = valid ? fmaxf(d_ap - d_an + 0.5f, 0.0f) : 0.0f;
        sv[wave] = valid ? 1.0f : 0.0f;
        sc[wave] = cls_part[r];
    }
    __syncthreads();
    if (threadIdx.x == 0)
        blk[blockIdx.x] = make_float4(sp[0] + sp[1] + sp[2] + sp[3],
                                      sv[0] + sv[1] + sv[2] + sv[3],
                                      sc[0] + sc[1] + sc[2] + sc[3], 0.f);
}

// ---------------- final combine: single block tree-reduces 2048 block partials ---------------
__global__ __launch_bounds__(1024) void fin_kernel(const float4* __restrict__ blk,
                                                   float* __restrict__ out) {
    __shared__ float sc[16], sp[16], sn[16];
    int t = threadIdx.x;
    int wave = t >> 6, lane = t & 63;
    float tp = 0.f, tv = 0.f, c = 0.f;
    for (int k = t; k < NRB; k += 1024) {
        float4 q = blk[k];
        tp += q.x;
        tv += q.y;
        c += q.z;
    }
#pragma unroll
    for (int o = 32; o >= 1; o >>= 1) {
        tp += __shfl_xor(tp, o);
        tv += __shfl_xor(tv, o);
        c += __shfl_xor(c, o);
    }
    if (lane == 0) { sp[wave] = tp; sn[wave] = tv; sc[wave] = c; }
    __syncthreads();
    if (t == 0) {
        float P = 0.f, V = 0.f, C = 0.f;
        for (int w = 0; w < 16; ++w) { P += sp[w]; V += sn[w]; C += sc[w]; }
        float tri = V > 0.5f ? P / V : 0.0f;
        out[0] = C * (1.0f / NB) + tri;
    }
}

extern "C" void kernel_launch(void* const* d_in, const int* in_sizes, int n_in,
                              void* d_out, int out_size, void* d_ws, size_t ws_size,
                              hipStream_t stream) {
    const float* logits = (const float*)d_in[0];
    const float* emb = (const float*)d_in[1];
    const int* labels = (const int*)d_in[2];

    char* w = (char*)d_ws;
    unsigned short* ebf = (unsigned short*)w;                 // 2 MB
    float* part = (float*)(w + 2097152);                      // NB*64 f32 (2 MB)
    float* cls_part = (float*)(w + 4194304);                  // NB f32 (32 KB)
    int* cnt = (int*)(w + 4227072);                           // NC int (4 KB)
    int* lists = (int*)(w + 4231168);                         // NC*CAP int (256 KB)
    float4* blk = (float4*)(w + 4493312);                     // NRB float4 (32 KB)

    ce_prep_kernel<<<NB / 4, 256, 0, stream>>>(logits, emb, labels, ebf, cls_part, cnt);
    mine_kernel<<<NPAIR, 256, 0, stream>>>(ebf, labels, cnt, lists, part);
    reduce_kernel<<<NRB, 256, 0, stream>>>(emb, labels, part, cnt, lists, cls_part, blk);
    fin_kernel<<<1, 1024, 0, stream>>>(blk, (float*)d_out);
}